// Round 3
// baseline (5417.097 us; speedup 1.0000x reference)
//
#include <hip/hip_runtime.h>

// ============================================================================
// DeepSpeech-like: FE(80->1024->2560, ReLU) -> BiLSTM(2560->2x256)
//                  -> BiLSTM(512->2x256) -> FC(512->29)
// I/O is fp32 (reference dtype). Internals: bf16 storage + MFMA, fp32 math.
// Arena: 156.9 MB with lifetime-based aliasing.
// ============================================================================

using u16 = unsigned short;
using u32 = unsigned int;
using bf16x8 = __attribute__((ext_vector_type(8))) short;
using f32x4  = __attribute__((ext_vector_type(4))) float;

__device__ __forceinline__ float bfu(u16 u) { return __uint_as_float((u32)u << 16); }
__device__ __forceinline__ u32 f2bf(float x) {            // RNE pack to bf16 bits
  u32 u = __float_as_uint(x);
  return (u + 0x7fffu + ((u >> 16) & 1u)) >> 16;
}
__device__ __forceinline__ float sigm(float x) {
  float e = __expf(-x);
  return __builtin_amdgcn_rcpf(1.f + e);
}
__device__ __forceinline__ float tanh_(float x) {
  float e = __expf(2.f * x);
  return 1.f - 2.f * __builtin_amdgcn_rcpf(1.f + e);
}
__device__ __forceinline__ void bf4(uint2 u, float* o) {
  o[0] = __uint_as_float(u.x << 16);
  o[1] = __uint_as_float(u.x & 0xffff0000u);
  o[2] = __uint_as_float(u.y << 16);
  o[3] = __uint_as_float(u.y & 0xffff0000u);
}

#define MF(a, b, c) __builtin_amdgcn_mfma_f32_16x16x32_bf16((a), (b), (c), 0, 0, 0)
#define GL2LDS(g, l) __builtin_amdgcn_global_load_lds( \
    (const __attribute__((address_space(1))) void*)(g), \
    (__attribute__((address_space(3))) void*)(l), 16, 0, 0)

// ---------------------------------------------------------------------------
// fp32 -> bf16 conversion helpers
// ---------------------------------------------------------------------------
__global__ __launch_bounds__(256) void cvt(const float* __restrict__ src,
                                           u16* __restrict__ dst, int n) {
  int i = (blockIdx.x * 256 + threadIdx.x) * 4;
  if (i < n) {   // n is a multiple of 4
    float4 v = *(const float4*)(src + i);
    u32 lo = f2bf(v.x) | (f2bf(v.y) << 16);
    u32 hi = f2bf(v.z) | (f2bf(v.w) << 16);
    *(uint2*)(dst + i) = make_uint2(lo, hi);
  }
}

// fp32 [R,80] -> bf16 [R,96] zero-padded
__global__ __launch_bounds__(256) void cvt_pad(const float* __restrict__ src,
                                               u16* __restrict__ dst, int total) {
  int i = blockIdx.x * 256 + threadIdx.x;
  if (i < total) {
    int r = i / 96, k = i - r * 96;
    float v = (k < 80) ? src[r * 80 + k] : 0.f;
    dst[i] = (u16)f2bf(v);
  }
}

__global__ void zero_flags(u32* f) { f[threadIdx.x] = 0u; }

// ---------------------------------------------------------------------------
// bf16 GEMM: out[M,N] = A[M,K] @ W[N,K]^T + b1 (+b2), biases fp32, m97-style.
// flags: bit0 = relu, bit2 = permute rows (in-row r=b*1000+t -> out-row t*16+b)
// Output always bf16.
// ---------------------------------------------------------------------------
__global__ __launch_bounds__(256) void gemm_bt(
    const u16* __restrict__ A, const u16* __restrict__ W,
    const float* __restrict__ b1, const float* __restrict__ b2,
    u16* __restrict__ out, int M, int N, int K, int flags)
{
  __shared__ __align__(16) u16 As[128 * 32];
  __shared__ __align__(16) u16 Bs[128 * 32];
  const int tid = threadIdx.x;
  const int lane = tid & 63, w = tid >> 6;
  const int q = lane >> 4, nh = lane & 15;
  const int bn0 = blockIdx.x * 128, bm0 = blockIdx.y * 128;
  const int wm = w & 1, wn = w >> 1;

  const f32x4 vzero = {0.f, 0.f, 0.f, 0.f};
  f32x4 acc[4][4];
#pragma unroll
  for (int a = 0; a < 4; ++a)
#pragma unroll
    for (int b = 0; b < 4; ++b) acc[a][b] = vzero;

  for (int k0 = 0; k0 < K; k0 += 32) {
#pragma unroll
    for (int i = 0; i < 2; ++i) {
      const int c = (i * 4 + w) * 64 + lane;   // 512 chunks of 16B per tile
      const int row = c >> 2, qq = c & 3;
      GL2LDS(A + (size_t)(bm0 + row) * K + k0 + qq * 8, (char*)As + c * 16);
      GL2LDS(W + (size_t)(bn0 + row) * K + k0 + qq * 8, (char*)Bs + c * 16);
    }
    __syncthreads();
    bf16x8 af[4], bfr[4];
#pragma unroll
    for (int mi = 0; mi < 4; ++mi)
      af[mi] = *(const bf16x8*)((const char*)As + (wm * 64 + mi * 16 + nh) * 64 + q * 16);
#pragma unroll
    for (int ni = 0; ni < 4; ++ni)
      bfr[ni] = *(const bf16x8*)((const char*)Bs + (wn * 64 + ni * 16 + nh) * 64 + q * 16);
#pragma unroll
    for (int mi = 0; mi < 4; ++mi)
#pragma unroll
      for (int ni = 0; ni < 4; ++ni)
        acc[mi][ni] = MF(af[mi], bfr[ni], acc[mi][ni]);
    __syncthreads();
  }

  const bool relu = flags & 1, perm = flags & 4;
#pragma unroll
  for (int ni = 0; ni < 4; ++ni) {
    const int gn = bn0 + wn * 64 + ni * 16 + nh;
    float bv = b1[gn];
    if (b2) bv += b2[gn];
#pragma unroll
    for (int mi = 0; mi < 4; ++mi) {
#pragma unroll
      for (int r = 0; r < 4; ++r) {
        const int gm = bm0 + wm * 64 + mi * 16 + q * 4 + r;
        float v = acc[mi][ni][r] + bv;
        if (relu) v = fmaxf(v, 0.f);
        size_t orow = perm ? (size_t)((gm % 1000) * 16 + gm / 1000) : (size_t)gm;
        out[orow * (size_t)N + gn] = (u16)f2bf(v);
      }
    }
  }
}

// ---------------------------------------------------------------------------
// Bidirectional LSTM layer recurrence. Grid = 4 blocks x 512 threads.
//   block 0,1: forward dir (hidden halves 0,1); block 2,3: backward dir.
// Each block owns 128 hidden units (512 gate cols); W_hh slice lives in
// registers as MFMA B-fragments. h exchanged via hseq + agent-scope flags.
// xg*: [1000][16][1024] bf16 (x@W_ih^T + b_ih + b_hh, PyTorch gate order).
// hseq: [1000][16][512] bf16 (fwd cols 0..255, bwd cols 256..511).
// ---------------------------------------------------------------------------
__global__ __launch_bounds__(512) void lstm_layer(
    const u16* __restrict__ xgF, const u16* __restrict__ xgB,
    const u16* __restrict__ whhF, const u16* __restrict__ whhB,
    u16* __restrict__ hseq, u32* flags)
{
  const int bid = blockIdx.x;
  const int dirb = bid >> 1;           // 0 fwd, 1 bwd
  const int half = bid & 1;            // hidden half owned
  const u16* xg  = dirb ? xgB : xgF;
  const u16* whh = dirb ? whhB : whhF;
  const int tid = threadIdx.x;
  const int w = tid >> 6, lane = tid & 63, q = lane >> 4, nh = lane & 15;
  const int gate = w >> 1, jq = (w & 1) * 64;   // wave: one gate, 64 local cols

  __shared__ __align__(16) u16 hbuf[16][272];   // h_{t-1}: [batch][hidden(+pad)]
  __shared__ __align__(16) float gl[16][512];   // gate pre-acts (local cols)

  // --- preload W_hh B-fragments: bw[tile][0..3]=own-k, [4..7]=partner-k ---
  bf16x8 bw[4][8];
#pragma unroll
  for (int tt = 0; tt < 4; ++tt) {
    const int N = gate * 256 + half * 128 + jq + tt * 16 + nh;
    const u16* wr = whh + (size_t)N * 256;
#pragma unroll
    for (int c2 = 0; c2 < 4; ++c2) {
      bw[tt][c2]     = *(const bf16x8*)(wr + (half * 4 + c2) * 32 + q * 8);
      bw[tt][4 + c2] = *(const bf16x8*)(wr + ((1 - half) * 4 + c2) * 32 + q * 8);
    }
  }

  const int me  = 2 * w + (lane >> 5);     // batch (elementwise ownership)
  const int jl4 = (lane & 31) * 4;         // local hidden, 4 per thread
  f32x4 cc = {0.f, 0.f, 0.f, 0.f};         // cell state, persistent in regs

  u32* myflag = flags + bid;
  u32* pflag  = flags + (bid ^ 1);
  const int kown = half * 128, kpar = 128 - kown;

  for (int s = 0; s < 1000; ++s) {
    const int ta = dirb ? (999 - s) : s;
    // prefetch xg for this step (consumed after MFMA)
    const u16* xrow = xg + ((size_t)ta * 16 + me) * 1024 + half * 128 + jl4;
    uint2 xiu = *(const uint2*)(xrow);
    uint2 xfu = *(const uint2*)(xrow + 256);
    uint2 xgu = *(const uint2*)(xrow + 512);
    uint2 xou = *(const uint2*)(xrow + 768);

    f32x4 a0 = {0.f,0.f,0.f,0.f}, a1 = a0, a2 = a0, a3 = a0;
    if (s > 0) {
      // own-half K first (no partner dependency)
#pragma unroll
      for (int c2 = 0; c2 < 4; ++c2) {
        bf16x8 a = *(const bf16x8*)(&hbuf[nh][kown + c2 * 32 + q * 8]);
        a0 = MF(a, bw[0][c2], a0); a1 = MF(a, bw[1][c2], a1);
        a2 = MF(a, bw[2][c2], a2); a3 = MF(a, bw[3][c2], a3);
      }
      if (w == 0) {  // wave 0: wait for partner's h(t-1), fetch into hbuf
        while (__hip_atomic_load(pflag, __ATOMIC_ACQUIRE, __HIP_MEMORY_SCOPE_AGENT) < (u32)s) {}
        const int tap = dirb ? (ta + 1) : (ta - 1);
        const u32* src = (const u32*)(hseq + (size_t)tap * 8192 + dirb * 256 + kpar);
#pragma unroll
        for (int i = 0; i < 16; ++i) {
          u32 v = src[(size_t)i * 256 + lane];
          *((u32*)&hbuf[i][kpar + lane * 2]) = v;
        }
      }
      __syncthreads();
#pragma unroll
      for (int c2 = 0; c2 < 4; ++c2) {
        bf16x8 a = *(const bf16x8*)(&hbuf[nh][kpar + c2 * 32 + q * 8]);
        a0 = MF(a, bw[0][4 + c2], a0); a1 = MF(a, bw[1][4 + c2], a1);
        a2 = MF(a, bw[2][4 + c2], a2); a3 = MF(a, bw[3][4 + c2], a3);
      }
    }
    // scatter gate pre-acts (h@Whh part) to LDS
#pragma unroll
    for (int r = 0; r < 4; ++r) {
      gl[q * 4 + r][gate * 128 + jq +      nh] = a0[r];
      gl[q * 4 + r][gate * 128 + jq + 16 + nh] = a1[r];
      gl[q * 4 + r][gate * 128 + jq + 32 + nh] = a2[r];
      gl[q * 4 + r][gate * 128 + jq + 48 + nh] = a3[r];
    }
    __syncthreads();
    // elementwise LSTM cell (4 (batch,hidden) cells per thread)
    f32x4 gi = *(const f32x4*)(&gl[me][jl4]);
    f32x4 gf = *(const f32x4*)(&gl[me][128 + jl4]);
    f32x4 gg = *(const f32x4*)(&gl[me][256 + jl4]);
    f32x4 go = *(const f32x4*)(&gl[me][384 + jl4]);
    float xi[4], xf[4], xgv[4], xo[4];
    bf4(xiu, xi); bf4(xfu, xf); bf4(xgu, xgv); bf4(xou, xo);
    float hv[4];
#pragma unroll
    for (int p = 0; p < 4; ++p) {
      float iv = sigm(gi[p] + xi[p]);
      float fv = sigm(gf[p] + xf[p]);
      float gv = tanh_(gg[p] + xgv[p]);
      float ov = sigm(go[p] + xo[p]);
      float c  = fv * cc[p] + iv * gv;
      cc[p] = c;
      hv[p] = ov * tanh_(c);
    }
    u32 lo = f2bf(hv[0]) | (f2bf(hv[1]) << 16);
    u32 hi = f2bf(hv[2]) | (f2bf(hv[3]) << 16);
    *((u32*)&hbuf[me][kown + jl4])     = lo;      // own half for next MFMA
    *((u32*)&hbuf[me][kown + jl4 + 2]) = hi;
    u32* gdst = (u32*)(hseq + ((size_t)ta * 16 + me) * 512 + dirb * 256 + kown + jl4);
    gdst[0] = lo; gdst[1] = hi;                    // output + partner exchange
    __syncthreads();                               // drains vmcnt for all waves
    if (tid == 0)
      __hip_atomic_store(myflag, (u32)(s + 1), __ATOMIC_RELEASE, __HIP_MEMORY_SCOPE_AGENT);
  }
}

// ---------------------------------------------------------------------------
// FC head: out[b][t][c] = h1[(t,b)] . fcw[c] + fcb[c]  (h1,fcw bf16; out fp32)
// ---------------------------------------------------------------------------
__global__ __launch_bounds__(256) void fc_kernel(
    const u16* __restrict__ h1, const u16* __restrict__ fcw,
    const float* __restrict__ fcb, float* __restrict__ out)
{
  __shared__ __align__(16) u16 wl[29 * 520];
  __shared__ __align__(16) u16 hl[8 * 520];
  const int tid = threadIdx.x;
  const int r0 = blockIdx.x * 8;
  for (int i = tid; i < 3712; i += 256) {          // 29 rows x 128 uint2
    int c = i >> 7, kk = i & 127;
    ((uint2*)wl)[c * 130 + kk] = ((const uint2*)fcw)[i];
  }
  for (int i = tid; i < 1024; i += 256) {          // 8 rows x 128 uint2
    int rr = i >> 7, kk = i & 127;
    ((uint2*)hl)[rr * 130 + kk] = ((const uint2*)(h1 + (size_t)r0 * 512))[i];
  }
  __syncthreads();
  const int c = tid & 31, rr = tid >> 5;
  if (c < 29) {
    const u16* hp = hl + rr * 520;
    const u16* wp = wl + c * 520;
    float acc = 0.f;
    for (int k = 0; k < 512; k += 4) {
      uint2 hv = *(const uint2*)(hp + k);
      uint2 wv = *(const uint2*)(wp + k);
      float A0 = __uint_as_float(hv.x << 16), A1 = __uint_as_float(hv.x & 0xffff0000u);
      float A2 = __uint_as_float(hv.y << 16), A3 = __uint_as_float(hv.y & 0xffff0000u);
      float B0 = __uint_as_float(wv.x << 16), B1 = __uint_as_float(wv.x & 0xffff0000u);
      float B2 = __uint_as_float(wv.y << 16), B3 = __uint_as_float(wv.y & 0xffff0000u);
      acc += A0 * B0 + A1 * B1 + A2 * B2 + A3 * B3;
    }
    const int r = r0 + rr, t = r >> 4, b = r & 15;
    out[((size_t)b * 1000 + t) * 29 + c] = acc + fcb[c];
  }
}

// ============================================================================
extern "C" void kernel_launch(void* const* d_in, const int* in_sizes, int n_in,
                              void* d_out, int out_size, void* d_ws, size_t ws_size,
                              hipStream_t stream) {
  (void)in_sizes; (void)n_in; (void)out_size; (void)ws_size;
  const float* x     = (const float*)d_in[0];
  const float* fw1   = (const float*)d_in[1];
  const float* fb1   = (const float*)d_in[2];
  const float* fw2   = (const float*)d_in[3];
  const float* fb2   = (const float*)d_in[4];
  const float* wih0f = (const float*)d_in[5];
  const float* whh0f = (const float*)d_in[6];
  const float* bih0f = (const float*)d_in[7];
  const float* bhh0f = (const float*)d_in[8];
  const float* wih0b = (const float*)d_in[9];
  const float* whh0b = (const float*)d_in[10];
  const float* bih0b = (const float*)d_in[11];
  const float* bhh0b = (const float*)d_in[12];
  const float* wih1f = (const float*)d_in[13];
  const float* whh1f = (const float*)d_in[14];
  const float* bih1f = (const float*)d_in[15];
  const float* bhh1f = (const float*)d_in[16];
  const float* wih1b = (const float*)d_in[17];
  const float* whh1b = (const float*)d_in[18];
  const float* bih1b = (const float*)d_in[19];
  const float* bhh1b = (const float*)d_in[20];
  const float* fcw   = (const float*)d_in[21];
  const float* fcb   = (const float*)d_in[22];
  float* out = (float*)d_out;

  // ---- arena with lifetime aliasing (total ~156.9 MB) ----
  char* ws = (char*)d_ws;
  u16* fe2  = (u16*)(ws);                    // [0, 81.92M) bf16, (b,t)-rows
  u16* xgA  = (u16*)(ws + 81920000);         // [81.92M, 114.688M)
  u16* xgB  = (u16*)(ws + 114688000);        // [114.688M, 147.456M)
  u16* fe1  = xgA;                           // alias: dead before xgA written
  // temporaries inside xgB region (dead before xgB written):
  u16* xb      = (u16*)(ws + 114688000);     // 16000x96 bf16  (3.072M)
  u16* w1b     = (u16*)(ws + 117760000);     // 1024x96        (0.197M)
  u16* w2b     = (u16*)(ws + 117956608);     // 2560x1024      (5.243M)
  u16* wih0fb  = (u16*)(ws + 123199488);     // 1024x2560      (5.243M)
  // persistent converted weights beyond the three big regions:
  u16* wih0bb  = (u16*)(ws + 147456000);     // 1024x2560      (5.243M)
  u16* whh0fb  = (u16*)(ws + 152698880);     // 1024x256       (0.524M)
  u16* whh0bb  = (u16*)(ws + 153223168);
  u16* wih1fb  = (u16*)(ws + 153747456);     // 1024x512       (1.049M)
  u16* wih1bb  = (u16*)(ws + 154796032);
  u16* whh1fb  = (u16*)(ws + 155844608);     // 1024x256
  u16* whh1bb  = (u16*)(ws + 156368896);
  u16* fcwb    = (u16*)(ws + 156893184);     // 29x512         (0.030M)
  // h0/h1/flags reuse the fe2 region once fe2 is dead:
  u16* h0   = (u16*)(ws);                    // 16000x512 bf16 (16.384M)
  u16* h1   = (u16*)(ws + 16384000);
  u32* flags = (u32*)(ws + 40000000);

  // ---- fp32 -> bf16 conversions ----
  hipLaunchKernelGGL(cvt_pad, dim3(6000), dim3(256), 0, stream, x,   xb,  1536000);
  hipLaunchKernelGGL(cvt_pad, dim3(384),  dim3(256), 0, stream, fw1, w1b, 98304);
  hipLaunchKernelGGL(cvt, dim3(2560), dim3(256), 0, stream, fw2,   w2b,    2621440);
  hipLaunchKernelGGL(cvt, dim3(2560), dim3(256), 0, stream, wih0f, wih0fb, 2621440);
  hipLaunchKernelGGL(cvt, dim3(2560), dim3(256), 0, stream, wih0b, wih0bb, 2621440);
  hipLaunchKernelGGL(cvt, dim3(256),  dim3(256), 0, stream, whh0f, whh0fb, 262144);
  hipLaunchKernelGGL(cvt, dim3(256),  dim3(256), 0, stream, whh0b, whh0bb, 262144);
  hipLaunchKernelGGL(cvt, dim3(512),  dim3(256), 0, stream, wih1f, wih1fb, 524288);
  hipLaunchKernelGGL(cvt, dim3(512),  dim3(256), 0, stream, wih1b, wih1bb, 524288);
  hipLaunchKernelGGL(cvt, dim3(256),  dim3(256), 0, stream, whh1f, whh1fb, 262144);
  hipLaunchKernelGGL(cvt, dim3(256),  dim3(256), 0, stream, whh1b, whh1bb, 262144);
  hipLaunchKernelGGL(cvt, dim3(15),   dim3(256), 0, stream, fcw,   fcwb,   14848);

  // FE1: [16000,96]@[1024,96]^T + b, ReLU -> fe1
  hipLaunchKernelGGL(gemm_bt, dim3(8, 125), dim3(256), 0, stream,
                     xb, w1b, fb1, (const float*)nullptr, fe1, 16000, 1024, 96, 1);
  // FE2: [16000,1024]@[2560,1024]^T + b, ReLU -> fe2
  hipLaunchKernelGGL(gemm_bt, dim3(20, 125), dim3(256), 0, stream,
                     fe1, w2b, fb2, (const float*)nullptr, fe2, 16000, 2560, 1024, 1);
  // L0 input gates (permuted to (t,b)-rows)
  hipLaunchKernelGGL(gemm_bt, dim3(8, 125), dim3(256), 0, stream,
                     fe2, wih0fb, bih0f, bhh0f, xgA, 16000, 1024, 2560, 4);
  hipLaunchKernelGGL(gemm_bt, dim3(8, 125), dim3(256), 0, stream,
                     fe2, wih0bb, bih0b, bhh0b, xgB, 16000, 1024, 2560, 4);
  // flags live in the (now dead) fe2 region -> zero them here
  hipLaunchKernelGGL(zero_flags, dim3(1), dim3(64), 0, stream, flags);
  // L0 recurrence
  hipLaunchKernelGGL(lstm_layer, dim3(4), dim3(512), 0, stream,
                     xgA, xgB, whh0fb, whh0bb, h0, flags);
  // L1 input gates (h0 rows already (t,b))
  hipLaunchKernelGGL(gemm_bt, dim3(8, 125), dim3(256), 0, stream,
                     h0, wih1fb, bih1f, bhh1f, xgA, 16000, 1024, 512, 0);
  hipLaunchKernelGGL(gemm_bt, dim3(8, 125), dim3(256), 0, stream,
                     h0, wih1bb, bih1b, bhh1b, xgB, 16000, 1024, 512, 0);
  // L1 recurrence
  hipLaunchKernelGGL(lstm_layer, dim3(4), dim3(512), 0, stream,
                     xgA, xgB, whh1fb, whh1bb, h1, flags + 16);
  // FC head -> fp32 out
  hipLaunchKernelGGL(fc_kernel, dim3(2000), dim3(256), 0, stream,
                     h1, fcwb, fcb, out);
}